// Round 7
// baseline (991.884 us; speedup 1.0000x reference)
//
#include <hip/hip_runtime.h>
#include <hip/hip_bf16.h>

// ColorINN: 8-layer coupling flow, B=524288 pts.
// R7: R4's validated structure (function-identical to scalar transcription),
// f32 inputs, *** f32 OUTPUT *** (reference returns jax f32 => d_out is float*).
// 1 wave / 128 pts; A-frags register-resident; f32 LDS h buffers.

#define MEMBAR() asm volatile("" ::: "memory")

typedef float f32x4 __attribute__((ext_vector_type(4)));
typedef short s16x8 __attribute__((ext_vector_type(8)));

#define MFMA(a,b,c) __builtin_amdgcn_mfma_f32_16x16x32_bf16((a),(b),(c),0,0,0)

__device__ __forceinline__ unsigned short f2bf(float f){
  unsigned u = __float_as_uint(f);
  return (unsigned short)((u + 0x7FFFu + ((u >> 16) & 1u)) >> 16);
}

// tanh-form GELU: x*(1 - 1/(1+exp2(x*(2.3022077 + 0.1029432 x^2))))
__device__ __forceinline__ float gelu_f(float x){
  float x2 = x*x;
  float w = x * __builtin_fmaf(0.1029432f, x2, 2.3022077f);
  float e = __builtin_amdgcn_exp2f(w);
  float r = __builtin_amdgcn_rcpf(1.0f + e);
  return __builtin_fmaf(-x, r, x);
}

__device__ __forceinline__ s16x8 pk8(f32x4 a, f32x4 b){
  s16x8 r;
  r[0]=(short)f2bf(a[0]); r[1]=(short)f2bf(a[1]);
  r[2]=(short)f2bf(a[2]); r[3]=(short)f2bf(a[3]);
  r[4]=(short)f2bf(b[0]); r[5]=(short)f2bf(b[1]);
  r[6]=(short)f2bf(b[2]); r[7]=(short)f2bf(b[3]);
  return r;
}

__global__ __launch_bounds__(64, 1) void inn_main(
    const float* __restrict__ XYZ,
    const float* __restrict__ W1, const float* __restrict__ b1,
    const float* __restrict__ W2, const float* __restrict__ b2,
    const float* __restrict__ W3, const float* __restrict__ b3,
    const float* __restrict__ gg, const float* __restrict__ off,
    const float* __restrict__ Pm,
    float* __restrict__ outp)
{
  __shared__ __align__(16) float hf1[16*132];   // h1[p][k], stride 132
  __shared__ __align__(16) float hf2[16*132];   // h2[p][k]
  __shared__ __align__(16) float xs[8*16*4];    // state [slot][p][4]

  const int lane = threadIdx.x;
  const int p = lane & 15;
  const int g = lane >> 4;
  const long base_pt = (long)blockIdx.x * 128;
  const f32x4 z4 = {0.f,0.f,0.f,0.f};

  if (lane < 16) {
    for (int s = 0; s < 8; ++s) {
      long pt = base_pt + s*16 + p;
      f32x4 v;
      v[0]=XYZ[pt*3+0]; v[1]=XYZ[pt*3+1]; v[2]=XYZ[pt*3+2]; v[3]=0.f;
      *(f32x4*)&xs[(s*16+p)*4] = v;
    }
  }
  MEMBAR();

  s16x8 aug = (s16x8){0,0,0,0,0,0,0,0};
  if (g == 0) aug[0] = (short)0x3F80;   // bf16(1.0) at k-slot 0

  for (int l = 0; l < 8; ++l) {
    // ---- A-fragments direct from global f32 (row = lane&15, k = 8*(lane>>4)+j) ----
    s16x8 A1[8];
    #pragma unroll
    for (int mf = 0; mf < 8; ++mf) {
      s16x8 t = (s16x8){0,0,0,0,0,0,0,0};
      if (g == 0) {
        int row = 16*mf + p;
        t[0] = (short)f2bf(W1[l*256 + row*2 + 0]);
        t[1] = (short)f2bf(W1[l*256 + row*2 + 1]);
        t[2] = (short)f2bf(b1[l*128 + row]);
      }
      A1[mf] = t;
    }
    s16x8 A2[8][4], A2b[8];
    #pragma unroll
    for (int mf = 0; mf < 8; ++mf) {
      const float* rw = W2 + l*16384 + (16*mf + p)*128 + 8*g;
      #pragma unroll
      for (int kc = 0; kc < 4; ++kc) {
        f32x4 u0 = *(const f32x4*)(rw + 32*kc);
        f32x4 u1 = *(const f32x4*)(rw + 32*kc + 4);
        A2[mf][kc] = pk8(u0, u1);
      }
      s16x8 t = (s16x8){0,0,0,0,0,0,0,0};
      if (g == 0) t[0] = (short)f2bf(b2[l*128 + 16*mf + p]);
      A2b[mf] = t;
    }
    s16x8 A3[4], A3b;
    #pragma unroll
    for (int kc = 0; kc < 4; ++kc) {
      s16x8 t = (s16x8){0,0,0,0,0,0,0,0};
      if (p < 4) {
        const float* rw = W3 + l*512 + p*128 + 8*g + 32*kc;
        f32x4 u0 = *(const f32x4*)(rw);
        f32x4 u1 = *(const f32x4*)(rw + 4);
        #pragma unroll
        for (int q = 0; q < 4; ++q) { u0[q]*=0.1f; u1[q]*=0.1f; }
        t = pk8(u0, u1);
      }
      A3[kc] = t;
    }
    {
      s16x8 t = (s16x8){0,0,0,0,0,0,0,0};
      if (g == 0 && p < 4) t[0] = (short)f2bf(0.1f*b3[l*4 + p]);
      A3b = t;
    }
    float scl[4];
    #pragma unroll
    for (int j = 0; j < 4; ++j)
      scl[j] = 0.2f * log1pf(expf(0.5f * gg[l*4 + j]));
    float PS[16], PB[4];
    #pragma unroll
    for (int i = 0; i < 4; ++i) {
      float acc = 0.f;
      #pragma unroll
      for (int j = 0; j < 4; ++j) {
        float pv = Pm[l*16 + 4*i + j];
        PS[4*i+j] = pv*scl[j];
        acc = __builtin_fmaf(pv, off[l*4+j], acc);
      }
      PB[i] = acc;
    }

    for (int s = 0; s < 8; ++s) {
      f32x4 xv = *(const f32x4*)&xs[(s*16+p)*4];

      // ---- G1 ----
      s16x8 bx = (s16x8){0,0,0,0,0,0,0,0};
      if (g == 0) { bx[0]=(short)f2bf(xv[0]); bx[1]=(short)f2bf(xv[1]); bx[2]=(short)0x3F80; }
      f32x4 c1[8];
      #pragma unroll
      for (int mf = 0; mf < 8; ++mf) c1[mf] = MFMA(A1[mf], bx, z4);

      MEMBAR();
      #pragma unroll
      for (int mf = 0; mf < 8; ++mf) {           // D row 16mf+4g+i, col p
        f32x4 hw;
        #pragma unroll
        for (int i = 0; i < 4; ++i) hw[i] = gelu_f(c1[mf][i]);
        *(f32x4*)&hf1[p*132 + 16*mf + 4*g] = hw;
      }
      MEMBAR();

      // ---- G2 ----
      f32x4 c2[8];
      #pragma unroll
      for (int mf = 0; mf < 8; ++mf) c2[mf] = MFMA(A2b[mf], aug, z4);
      #pragma unroll
      for (int kc = 0; kc < 4; ++kc) {
        const float* hr = &hf1[p*132 + 32*kc + 8*g];
        f32x4 u0 = *(const f32x4*)hr;
        f32x4 u1 = *(const f32x4*)(hr + 4);
        s16x8 bfr = pk8(u0, u1);
        #pragma unroll
        for (int mf = 0; mf < 8; ++mf) c2[mf] = MFMA(A2[mf][kc], bfr, c2[mf]);
      }

      MEMBAR();
      #pragma unroll
      for (int mf = 0; mf < 8; ++mf) {
        f32x4 hw;
        #pragma unroll
        for (int i = 0; i < 4; ++i) hw[i] = gelu_f(c2[mf][i]);
        *(f32x4*)&hf2[p*132 + 16*mf + 4*g] = hw;
      }
      MEMBAR();

      // ---- G3 ----
      f32x4 c3 = MFMA(A3b, aug, z4);
      #pragma unroll
      for (int kc = 0; kc < 4; ++kc) {
        const float* hr = &hf2[p*132 + 32*kc + 8*g];
        f32x4 u0 = *(const f32x4*)hr;
        f32x4 u1 = *(const f32x4*)(hr + 4);
        s16x8 bfr = pk8(u0, u1);
        c3 = MFMA(A3[kc], bfr, c3);
      }

      // a[0..3] live on lanes 0..15 (rows 0..3), broadcast to all
      int addr = p << 2;
      float a0 = __int_as_float(__builtin_amdgcn_ds_bpermute(addr, __float_as_int(c3[0])));
      float a1 = __int_as_float(__builtin_amdgcn_ds_bpermute(addr, __float_as_int(c3[1])));
      float a2 = __int_as_float(__builtin_amdgcn_ds_bpermute(addr, __float_as_int(c3[2])));
      float a3 = __int_as_float(__builtin_amdgcn_ds_bpermute(addr, __float_as_int(c3[3])));

      // tail: s=2tanh(a) => exp(s) = exp2(2.8853901 - 5.7707802/(1+exp2(2.8853901*a)))
      float t0 = __builtin_amdgcn_rcpf(1.f + __builtin_amdgcn_exp2f(2.8853901f * a0));
      float t1 = __builtin_amdgcn_rcpf(1.f + __builtin_amdgcn_exp2f(2.8853901f * a1));
      float e0 = __builtin_amdgcn_exp2f(__builtin_fmaf(-5.7707802f, t0, 2.8853901f));
      float e1 = __builtin_amdgcn_exp2f(__builtin_fmaf(-5.7707802f, t1, 2.8853901f));
      float v2 = __builtin_fmaf(xv[2], e0, a2);
      float v3 = __builtin_fmaf(xv[3], e1, a3);
      f32x4 y;
      #pragma unroll
      for (int i = 0; i < 4; ++i)
        y[i] = __builtin_fmaf(PS[4*i+0], xv[0], __builtin_fmaf(PS[4*i+1], xv[1],
               __builtin_fmaf(PS[4*i+2], v2, __builtin_fmaf(PS[4*i+3], v3, PB[i]))));
      if (g == 0) *(f32x4*)&xs[(s*16+p)*4] = y;
      MEMBAR();
    }
  }

  if (lane < 16) {
    for (int s = 0; s < 8; ++s) {
      long pt = base_pt + s*16 + p;
      f32x4 xv = *(const f32x4*)&xs[(s*16+p)*4];
      outp[pt*3+0] = xv[0];
      outp[pt*3+1] = xv[1];
      outp[pt*3+2] = xv[2];
    }
  }
}

extern "C" void kernel_launch(void* const* d_in, const int* in_sizes, int n_in,
                              void* d_out, int out_size, void* d_ws, size_t ws_size,
                              hipStream_t stream)
{
  const float* XYZ = (const float*)d_in[0];
  const float* W1  = (const float*)d_in[1];
  const float* b1  = (const float*)d_in[2];
  const float* W2  = (const float*)d_in[3];
  const float* b2  = (const float*)d_in[4];
  const float* W3  = (const float*)d_in[5];
  const float* b3  = (const float*)d_in[6];
  const float* g   = (const float*)d_in[7];
  const float* off = (const float*)d_in[8];
  const float* P   = (const float*)d_in[9];

  int Bn = in_sizes[0] / 3;          // 524288
  int nblocks = Bn / 128;            // 4096 exact
  inn_main<<<nblocks, 64, 0, stream>>>(XYZ, W1, b1, W2, b2, W3, b3, g, off, P,
                                       (float*)d_out);
}

// Round 8
// 496.824 us; speedup vs baseline: 1.9964x; 1.9964x over previous
//
#include <hip/hip_runtime.h>
#include <hip/hip_bf16.h>

// ColorINN R8: occupancy + VALU-cut round.
// 256-thread blocks (4 waves), each wave 128 pts. A2 (+b2 chunk) staged in LDS
// per layer (shared by all 4 waves); state in registers; h staged as packed
// bf16 in the R2-verified byte layout; all packing via v_cvt_pk_bf16_f32.

#define MEMBAR() asm volatile("" ::: "memory")

typedef float f32x4 __attribute__((ext_vector_type(4)));
typedef short s16x8 __attribute__((ext_vector_type(8)));
typedef short s16x4 __attribute__((ext_vector_type(4)));
typedef int   i32x4 __attribute__((ext_vector_type(4)));

#define MFMA(a,b,c) __builtin_amdgcn_mfma_f32_16x16x32_bf16((a),(b),(c),0,0,0)

__device__ __forceinline__ unsigned cvtpk(float a, float b){
  unsigned r;
  asm("v_cvt_pk_bf16_f32 %0, %1, %2" : "=v"(r) : "v"(a), "v"(b));
  return r;   // lo = bf16(a), hi = bf16(b)
}
__device__ __forceinline__ unsigned short f2bf(float f){
  unsigned u = __float_as_uint(f);
  return (unsigned short)((u + 0x7FFFu + ((u >> 16) & 1u)) >> 16);
}

// tanh-form GELU: x*(1 - 1/(1+exp2(x*(2.3022077 + 0.1029432 x^2))))
__device__ __forceinline__ float gelu_f(float x){
  float x2 = x*x;
  float w = x * __builtin_fmaf(0.1029432f, x2, 2.3022077f);
  float e = __builtin_amdgcn_exp2f(w);
  float r = __builtin_amdgcn_rcpf(1.0f + e);
  return __builtin_fmaf(-x, r, x);
}

__global__ __launch_bounds__(256, 2) void inn_main(
    const float* __restrict__ XYZ,
    const float* __restrict__ W1, const float* __restrict__ b1,
    const float* __restrict__ W2, const float* __restrict__ b2,
    const float* __restrict__ W3, const float* __restrict__ b3,
    const float* __restrict__ gg, const float* __restrict__ off,
    const float* __restrict__ Pm,
    float* __restrict__ outp)
{
  // A2: 40 frags (mf*5+kc; kc==4 = b2 chunk) x 1KB. h: 4 waves x 4352B.
  __shared__ __align__(16) unsigned char ldsA2[40*1024];
  __shared__ __align__(16) unsigned char ldsH[4*4352];

  const int tid  = threadIdx.x;
  const int wid  = tid >> 6;
  const int lane = tid & 63;
  const int p    = lane & 15;
  const int g    = lane >> 4;
  unsigned char* hb = ldsH + wid*4352;
  const long base_pt = (long)blockIdx.x*512 + wid*128;
  const f32x4 z4 = {0.f,0.f,0.f,0.f};

  // per-point state in registers (statically indexed)
  f32x4 xst[8];
  #pragma unroll
  for (int s = 0; s < 8; ++s) {
    long pt = base_pt + s*16 + p;
    xst[s][0] = XYZ[pt*3+0];
    xst[s][1] = XYZ[pt*3+1];
    xst[s][2] = XYZ[pt*3+2];
    xst[s][3] = 0.f;
  }

  s16x8 aug = (s16x8){0,0,0,0,0,0,0,0};
  if (g == 0) aug[0] = (short)0x3F80;   // bf16(1.0) at k-slot 0

  for (int l = 0; l < 8; ++l) {
    __syncthreads();   // prev layer's A2 reads complete before overwrite

    // ---- cooperative A2 staging: warp wid stages frags wid*10 .. wid*10+9 ----
    #pragma unroll
    for (int q = 0; q < 10; ++q) {
      int mf = wid*2 + (q >= 5 ? 1 : 0);
      int kc = (q >= 5) ? q - 5 : q;
      int f  = mf*5 + kc;
      s16x8 frag = (s16x8){0,0,0,0,0,0,0,0};
      if (kc < 4) {
        const float* rw = W2 + l*16384 + (16*mf + p)*128 + 32*kc + 8*g;
        f32x4 u0 = *(const f32x4*)rw;
        f32x4 u1 = *(const f32x4*)(rw + 4);
        i32x4 w;
        w[0] = (int)cvtpk(u0[0], u0[1]); w[1] = (int)cvtpk(u0[2], u0[3]);
        w[2] = (int)cvtpk(u1[0], u1[1]); w[3] = (int)cvtpk(u1[2], u1[3]);
        __builtin_memcpy(&frag, &w, 16);
      } else {
        if (lane < 16) frag[0] = (short)f2bf(b2[l*128 + 16*mf + lane]);
      }
      *(s16x8*)(ldsA2 + f*1024 + lane*16) = frag;
    }

    // ---- per-wave register fragments: A1 (W1+b1 aug), A3 (0.1*W3 + 0.1*b3) ----
    s16x8 A1[8];
    #pragma unroll
    for (int mf = 0; mf < 8; ++mf) {
      s16x8 t = (s16x8){0,0,0,0,0,0,0,0};
      if (g == 0) {
        int row = 16*mf + p;
        t[0] = (short)f2bf(W1[l*256 + row*2 + 0]);
        t[1] = (short)f2bf(W1[l*256 + row*2 + 1]);
        t[2] = (short)f2bf(b1[l*128 + row]);
      }
      A1[mf] = t;
    }
    s16x8 A3[4], A3b;
    #pragma unroll
    for (int kc = 0; kc < 4; ++kc) {
      s16x8 t = (s16x8){0,0,0,0,0,0,0,0};
      if (p < 4) {
        const float* rw = W3 + l*512 + p*128 + 8*g + 32*kc;
        f32x4 u0 = *(const f32x4*)(rw);
        f32x4 u1 = *(const f32x4*)(rw + 4);
        i32x4 w;
        w[0] = (int)cvtpk(0.1f*u0[0], 0.1f*u0[1]); w[1] = (int)cvtpk(0.1f*u0[2], 0.1f*u0[3]);
        w[2] = (int)cvtpk(0.1f*u1[0], 0.1f*u1[1]); w[3] = (int)cvtpk(0.1f*u1[2], 0.1f*u1[3]);
        __builtin_memcpy(&t, &w, 16);
      }
      A3[kc] = t;
    }
    {
      s16x8 t = (s16x8){0,0,0,0,0,0,0,0};
      if (g == 0 && p < 4) t[0] = (short)f2bf(0.1f*b3[l*4 + p]);
      A3b = t;
    }
    float scl[4];
    #pragma unroll
    for (int j = 0; j < 4; ++j)
      scl[j] = 0.2f * log1pf(expf(0.5f * gg[l*4 + j]));
    float PS[16], PB[4];
    #pragma unroll
    for (int i = 0; i < 4; ++i) {
      float acc = 0.f;
      #pragma unroll
      for (int j = 0; j < 4; ++j) {
        float pv = Pm[l*16 + 4*i + j];
        PS[4*i+j] = pv*scl[j];
        acc = __builtin_fmaf(pv, off[l*4+j], acc);
      }
      PB[i] = acc;
    }

    __syncthreads();   // A2 staged before any wave reads it

    #pragma unroll
    for (int s = 0; s < 8; ++s) {
      // ---- G1: h1 = gelu(W1aug @ [x0;x1;1]) ----
      s16x8 bx = (s16x8){0,0,0,0,0,0,0,0};
      if (g == 0) {
        unsigned b01 = cvtpk(xst[s][0], xst[s][1]);
        bx[0] = (short)(b01 & 0xFFFFu);
        bx[1] = (short)(b01 >> 16);
        bx[2] = (short)0x3F80;
      }
      f32x4 c1[8];
      #pragma unroll
      for (int mf = 0; mf < 8; ++mf) c1[mf] = MFMA(A1[mf], bx, z4);

      MEMBAR();
      #pragma unroll
      for (int m = 0; m < 4; ++m) {     // packed-bf16 h write, R2-verified layout
        i32x4 w;
        w[0] = (int)cvtpk(gelu_f(c1[2*m][0]),   gelu_f(c1[2*m][1]));
        w[1] = (int)cvtpk(gelu_f(c1[2*m][2]),   gelu_f(c1[2*m][3]));
        w[2] = (int)cvtpk(gelu_f(c1[2*m+1][0]), gelu_f(c1[2*m+1][1]));
        w[3] = (int)cvtpk(gelu_f(c1[2*m+1][2]), gelu_f(c1[2*m+1][3]));
        *(i32x4*)(hb + p*272 + (4*m + g)*16) = w;
      }
      MEMBAR();

      // ---- G2: h2 = gelu(W2 @ h1 + b2) ----
      f32x4 c2[8];
      #pragma unroll
      for (int mf = 0; mf < 8; ++mf) {
        s16x8 ab = *(const s16x8*)(ldsA2 + (mf*5 + 4)*1024 + lane*16);
        c2[mf] = MFMA(ab, aug, z4);
      }
      #pragma unroll
      for (int kc = 0; kc < 4; ++kc) {
        const unsigned char* ra = hb + p*272 + (4*kc + 2*(g & 1))*16 + (g >> 1)*8;
        s16x4 lo = *(const s16x4*)(ra);
        s16x4 hi = *(const s16x4*)(ra + 16);
        s16x8 bfr = __builtin_shufflevector(lo, hi, 0,1,2,3,4,5,6,7);
        #pragma unroll
        for (int mf = 0; mf < 8; ++mf) {
          s16x8 af = *(const s16x8*)(ldsA2 + (mf*5 + kc)*1024 + lane*16);
          c2[mf] = MFMA(af, bfr, c2[mf]);
        }
      }

      MEMBAR();
      #pragma unroll
      for (int m = 0; m < 4; ++m) {     // h2 overwrites h1 (sequential use)
        i32x4 w;
        w[0] = (int)cvtpk(gelu_f(c2[2*m][0]),   gelu_f(c2[2*m][1]));
        w[1] = (int)cvtpk(gelu_f(c2[2*m][2]),   gelu_f(c2[2*m][3]));
        w[2] = (int)cvtpk(gelu_f(c2[2*m+1][0]), gelu_f(c2[2*m+1][1]));
        w[3] = (int)cvtpk(gelu_f(c2[2*m+1][2]), gelu_f(c2[2*m+1][3]));
        *(i32x4*)(hb + p*272 + (4*m + g)*16) = w;
      }
      MEMBAR();

      // ---- G3: a = 0.1*(W3 @ h2 + b3) ----
      f32x4 c3 = MFMA(A3b, aug, z4);
      #pragma unroll
      for (int kc = 0; kc < 4; ++kc) {
        const unsigned char* ra = hb + p*272 + (4*kc + 2*(g & 1))*16 + (g >> 1)*8;
        s16x4 lo = *(const s16x4*)(ra);
        s16x4 hi = *(const s16x4*)(ra + 16);
        s16x8 bfr = __builtin_shufflevector(lo, hi, 0,1,2,3,4,5,6,7);
        c3 = MFMA(A3[kc], bfr, c3);
      }

      // broadcast a[0..3] (rows 0..3 live on lanes 0..15) to all lanes
      int addr = p << 2;
      float a0 = __int_as_float(__builtin_amdgcn_ds_bpermute(addr, __float_as_int(c3[0])));
      float a1 = __int_as_float(__builtin_amdgcn_ds_bpermute(addr, __float_as_int(c3[1])));
      float a2 = __int_as_float(__builtin_amdgcn_ds_bpermute(addr, __float_as_int(c3[2])));
      float a3 = __int_as_float(__builtin_amdgcn_ds_bpermute(addr, __float_as_int(c3[3])));

      // tail: s=2tanh(a) => exp(s) = exp2(2.8853901 - 5.7707802/(1+exp2(2.8853901*a)))
      float t0 = __builtin_amdgcn_rcpf(1.f + __builtin_amdgcn_exp2f(2.8853901f * a0));
      float t1 = __builtin_amdgcn_rcpf(1.f + __builtin_amdgcn_exp2f(2.8853901f * a1));
      float e0 = __builtin_amdgcn_exp2f(__builtin_fmaf(-5.7707802f, t0, 2.8853901f));
      float e1 = __builtin_amdgcn_exp2f(__builtin_fmaf(-5.7707802f, t1, 2.8853901f));
      float v2 = __builtin_fmaf(xst[s][2], e0, a2);
      float v3 = __builtin_fmaf(xst[s][3], e1, a3);
      f32x4 y;
      #pragma unroll
      for (int i = 0; i < 4; ++i)
        y[i] = __builtin_fmaf(PS[4*i+0], xst[s][0], __builtin_fmaf(PS[4*i+1], xst[s][1],
               __builtin_fmaf(PS[4*i+2], v2, __builtin_fmaf(PS[4*i+3], v3, PB[i]))));
      xst[s] = y;   // replicated across all lanes
    }
  }

  if (g == 0) {
    #pragma unroll
    for (int s = 0; s < 8; ++s) {
      long pt = base_pt + s*16 + p;
      outp[pt*3+0] = xst[s][0];
      outp[pt*3+1] = xst[s][1];
      outp[pt*3+2] = xst[s][2];
    }
  }
}

extern "C" void kernel_launch(void* const* d_in, const int* in_sizes, int n_in,
                              void* d_out, int out_size, void* d_ws, size_t ws_size,
                              hipStream_t stream)
{
  const float* XYZ = (const float*)d_in[0];
  const float* W1  = (const float*)d_in[1];
  const float* b1  = (const float*)d_in[2];
  const float* W2  = (const float*)d_in[3];
  const float* b2  = (const float*)d_in[4];
  const float* W3  = (const float*)d_in[5];
  const float* b3  = (const float*)d_in[6];
  const float* g   = (const float*)d_in[7];
  const float* off = (const float*)d_in[8];
  const float* P   = (const float*)d_in[9];

  int Bn = in_sizes[0] / 3;          // 524288
  int nblocks = Bn / 512;            // 1024 exact
  inn_main<<<nblocks, 256, 0, stream>>>(XYZ, W1, b1, W2, b2, W3, b3, g, off, P,
                                        (float*)d_out);
}